// Round 1
// baseline (1468.082 us; speedup 1.0000x reference)
//
#include <hip/hip_runtime.h>
#include <hip/hip_bf16.h>
#include <math.h>

#define NB 4
#define B  2048
#define L  168
#define DI 9
#define H  96
#define N2 48

#define LSTR 188   // ut row stride (floats), 8-float zero front pad
#define ZSTR 172   // z2t row stride

__device__ __forceinline__ float gelu_f(float x) {
    float x3 = x * x * x;
    float y  = 0.7978845608028654f * (x + 0.044715f * x3);
    float ey = __expf(2.0f * y);
    float t  = 1.0f - 2.0f / (ey + 1.0f);
    return 0.5f * x * (1.0f + t);
}

// ---------------- S4D kernel generation: K[i][h][l] ----------------
__global__ void kgen_kernel(const float* __restrict__ log_dt, const float* __restrict__ lar,
                            const float* __restrict__ aim, const float* __restrict__ cre,
                            const float* __restrict__ cim, float* __restrict__ K)
{
    const int ih   = blockIdx.x;      // i*96+h, 384 blocks
    const int lane = threadIdx.x;     // 64
    float ctre = 0.f, ctim = 0.f, pre = 0.f, pim = 0.f, mre = 0.f, mim = 0.f;
    if (lane < N2) {
        float dt  = expf(log_dt[ih]);
        int   idx = ih * N2 + lane;
        float reA = -expf(lar[idx]);
        float imA = aim[idx];
        float dre = dt * reA, dim = dt * imA;
        float er  = expf(dre);
        float sv, cv;
        sincosf(dim, &sv, &cv);
        mre = er * cv; mim = er * sv;              // exp(dtA)
        float nre = mre - 1.0f, nim = mim;         // exp(dtA)-1
        float den = reA * reA + imA * imA;
        float tre = (nre * reA + nim * imA) / den; // (exp(dtA)-1)/A
        float tim = (nim * reA - nre * imA) / den;
        float cr = cre[idx], ci = cim[idx];
        ctre = cr * tre - ci * tim;                // Ct
        ctim = cr * tim + ci * tre;
        pre = 1.0f; pim = 0.0f;                    // exp(dtA*0)
    }
    float* Kr = K + ih * L;
    for (int l = 0; l < L; ++l) {
        float term = ctre * pre - ctim * pim;      // Re(Ct * p)
        #pragma unroll
        for (int off = 32; off > 0; off >>= 1) term += __shfl_xor(term, off, 64);
        if (lane == 0) Kr[l] = 2.0f * term;
        float nr = pre * mre - pim * mim;
        float ni = pre * mim + pim * mre;
        pre = nr; pim = ni;
    }
}

// ---------------- encoder: h[b,l,:] = x[b,l,:] @ enc_W + enc_b ----------------
__launch_bounds__(256)
__global__ void enc_kernel(const float* __restrict__ x, const float* __restrict__ W,
                           const float* __restrict__ bias, float* __restrict__ h)
{
    __shared__ float Ws[DI * H];
    __shared__ float bs[H];
    const int tid = threadIdx.x;
    for (int e = tid; e < DI * H; e += 256) Ws[e] = W[e];
    if (tid < H) bs[tid] = bias[tid];
    __syncthreads();
    const int total = B * L * H;
    for (int idx = blockIdx.x * 256 + tid; idx < total; idx += 2048 * 256) {
        int r = idx / H, c = idx - r * H;
        const float* xr = x + r * DI;
        float a = bs[c];
        #pragma unroll
        for (int k = 0; k < DI; ++k) a = fmaf(xr[k], Ws[k * H + c], a);
        h[idx] = a;
    }
}

// ---------------- fused S4 block: conv+skip -> gelu -> @W_out+b -> residual LN, in-place ----------------
__launch_bounds__(512, 2)
__global__ void s4_block(float* __restrict__ hbuf, const float* __restrict__ Kg,
                         const float* __restrict__ Wg, const float* __restrict__ bout,
                         const float* __restrict__ Dsk, const float* __restrict__ lnw,
                         const float* __restrict__ lnb)
{
    __shared__ float smem[32 * LSTR + 32 * ZSTR + 2 * 176];
    float* ut   = smem;                       // [32][LSTR]   u chunk, transposed, front-padded
    float* z2t  = smem + 32 * LSTR;           // [32][ZSTR]   gelu output chunk, transposed
    float* muA  = smem + 32 * LSTR + 32 * ZSTR;
    float* rsA  = muA + 176;
    float* psum = smem;                       // overlay after matmul done: [24][176]
    float* psq  = smem + 24 * 176;

    const int tid = threadIdx.x;
    const int b   = blockIdx.x;
    float* __restrict__ hb = hbuf + (size_t)b * (L * H);

    // zero front pads once
    for (int e = tid; e < 32 * 8; e += 512) ut[(e >> 3) * LSTR + (e & 7)] = 0.0f;

    const int  mt  = tid;
    const bool act = mt < 504;
    const int  mlt = mt / 24, mhc = mt % 24;
    const int  ml0 = mlt * 8;
    float acc2[8][4];
    #pragma unroll
    for (int i = 0; i < 8; ++i) { acc2[i][0] = acc2[i][1] = acc2[i][2] = acc2[i][3] = 0.f; }

    for (int ch = 0; ch < 3; ++ch) {
        __syncthreads();
        // stage u chunk rows (transposed): ut[hl][8+l] = u[l][ch*32+hl]
        for (int e = tid; e < 32 * L; e += 512) {
            int l = e >> 5, kl = e & 31;
            ut[kl * LSTR + 8 + l] = hb[l * H + ch * 32 + kl];
        }
        __syncthreads();
        // conv + skip + gelu: tasks = ltile(21) * 32 h_local
        for (int pass = 0; pass < 2; ++pass) {
            int task = tid + pass * 512;
            if (task < 672) {
                int lt = task >> 5, hl = task & 31;
                int l0 = lt * 8;
                int h  = ch * 32 + hl;
                const float* Krow = Kg + h * L;
                const float* urow = ut + hl * LSTR;
                float acc[8] = {0, 0, 0, 0, 0, 0, 0, 0};
                for (int d0 = 0; d0 <= l0; d0 += 8) {
                    const float* up = urow + (l0 - d0);
                    float4 A0 = *(const float4*)(up);
                    float4 A1 = *(const float4*)(up + 4);
                    float4 A2 = *(const float4*)(up + 8);
                    float4 A3 = *(const float4*)(up + 12);
                    float uv[16] = {A0.x, A0.y, A0.z, A0.w, A1.x, A1.y, A1.z, A1.w,
                                    A2.x, A2.y, A2.z, A2.w, A3.x, A3.y, A3.z, A3.w};
                    float4 K0 = *(const float4*)(Krow + d0);
                    float4 K1 = *(const float4*)(Krow + d0 + 4);
                    float kv[8] = {K0.x, K0.y, K0.z, K0.w, K1.x, K1.y, K1.z, K1.w};
                    #pragma unroll
                    for (int dd = 0; dd < 8; ++dd) {
                        #pragma unroll
                        for (int i = 0; i < 8; ++i)
                            acc[i] = fmaf(kv[dd], uv[8 + i - dd], acc[i]);
                    }
                }
                float  ds = Dsk[h];
                float4 U0 = *(const float4*)(urow + 8 + l0);
                float4 U1 = *(const float4*)(urow + 12 + l0);
                float uc[8] = {U0.x, U0.y, U0.z, U0.w, U1.x, U1.y, U1.z, U1.w};
                float zo[8];
                #pragma unroll
                for (int i = 0; i < 8; ++i) zo[i] = gelu_f(fmaf(ds, uc[i], acc[i]));
                float* zrow = z2t + hl * ZSTR + l0;
                *(float4*)(zrow)     = make_float4(zo[0], zo[1], zo[2], zo[3]);
                *(float4*)(zrow + 4) = make_float4(zo[4], zo[5], zo[6], zo[7]);
            }
        }
        __syncthreads();
        // partial matmul over this k-chunk: acc2 += z2t[k][l-tile] * W[k][h'-tile]
        if (act) {
            const float* Wc = Wg + ch * 32 * H + mhc * 4;
            #pragma unroll 2
            for (int kl = 0; kl < 32; ++kl) {
                float4 w4 = *(const float4*)(Wc + kl * H);
                const float* zr = z2t + kl * ZSTR + ml0;
                float4 a0 = *(const float4*)(zr);
                float4 a1 = *(const float4*)(zr + 4);
                float av[8] = {a0.x, a0.y, a0.z, a0.w, a1.x, a1.y, a1.z, a1.w};
                #pragma unroll
                for (int i = 0; i < 8; ++i) {
                    acc2[i][0] = fmaf(av[i], w4.x, acc2[i][0]);
                    acc2[i][1] = fmaf(av[i], w4.y, acc2[i][1]);
                    acc2[i][2] = fmaf(av[i], w4.z, acc2[i][2]);
                    acc2[i][3] = fmaf(av[i], w4.w, acc2[i][3]);
                }
            }
        }
    }
    // bias + residual (global reads, before any write)
    if (act) {
        float4 bo = *(const float4*)(bout + mhc * 4);
        #pragma unroll
        for (int i = 0; i < 8; ++i) {
            float4 r = *(const float4*)(hb + (ml0 + i) * H + mhc * 4);
            acc2[i][0] += bo.x + r.x;
            acc2[i][1] += bo.y + r.y;
            acc2[i][2] += bo.z + r.z;
            acc2[i][3] += bo.w + r.w;
        }
    }
    __syncthreads();   // all LDS matmul reads done -> safe to overlay psum/psq
    if (act) {
        #pragma unroll
        for (int i = 0; i < 8; ++i) {
            float s = acc2[i][0] + acc2[i][1] + acc2[i][2] + acc2[i][3];
            float q = acc2[i][0] * acc2[i][0] + acc2[i][1] * acc2[i][1] +
                      acc2[i][2] * acc2[i][2] + acc2[i][3] * acc2[i][3];
            psum[mhc * 176 + ml0 + i] = s;
            psq [mhc * 176 + ml0 + i] = q;
        }
    }
    __syncthreads();
    if (tid < L) {
        float s = 0.f, q = 0.f;
        #pragma unroll 4
        for (int c = 0; c < 24; ++c) { s += psum[c * 176 + tid]; q += psq[c * 176 + tid]; }
        float m = s * (1.0f / 96.0f);
        float v = q * (1.0f / 96.0f) - m * m;
        muA[tid] = m;
        rsA[tid] = rsqrtf(v + 1e-5f);
    }
    __syncthreads();
    if (act) {
        float4 w4 = *(const float4*)(lnw + mhc * 4);
        float4 b4 = *(const float4*)(lnb + mhc * 4);
        #pragma unroll
        for (int i = 0; i < 8; ++i) {
            float m = muA[ml0 + i], r = rsA[ml0 + i];
            float4 o;
            o.x = fmaf((acc2[i][0] - m) * r, w4.x, b4.x);
            o.y = fmaf((acc2[i][1] - m) * r, w4.y, b4.y);
            o.z = fmaf((acc2[i][2] - m) * r, w4.z, b4.z);
            o.w = fmaf((acc2[i][3] - m) * r, w4.w, b4.w);
            *(float4*)(hb + (ml0 + i) * H + mhc * 4) = o;
        }
    }
}

// ---------------- decoder: h = h @ dec_W + dec_b, in-place per b ----------------
__launch_bounds__(512, 2)
__global__ void dec_kernel(float* __restrict__ hbuf, const float* __restrict__ Wg,
                           const float* __restrict__ bias)
{
    __shared__ float ht[32 * ZSTR];
    const int tid = threadIdx.x;
    const int b   = blockIdx.x;
    float* __restrict__ hb = hbuf + (size_t)b * (L * H);
    const int  mt  = tid;
    const bool act = mt < 504;
    const int  mlt = mt / 24, mhc = mt % 24;
    const int  ml0 = mlt * 8;
    float acc2[8][4];
    #pragma unroll
    for (int i = 0; i < 8; ++i) { acc2[i][0] = acc2[i][1] = acc2[i][2] = acc2[i][3] = 0.f; }

    for (int ch = 0; ch < 3; ++ch) {
        __syncthreads();
        for (int e = tid; e < 32 * L; e += 512) {
            int l = e >> 5, kl = e & 31;
            ht[kl * ZSTR + l] = hb[l * H + ch * 32 + kl];
        }
        __syncthreads();
        if (act) {
            const float* Wc = Wg + ch * 32 * H + mhc * 4;
            #pragma unroll 2
            for (int kl = 0; kl < 32; ++kl) {
                float4 w4 = *(const float4*)(Wc + kl * H);
                const float* zr = ht + kl * ZSTR + ml0;
                float4 a0 = *(const float4*)(zr);
                float4 a1 = *(const float4*)(zr + 4);
                float av[8] = {a0.x, a0.y, a0.z, a0.w, a1.x, a1.y, a1.z, a1.w};
                #pragma unroll
                for (int i = 0; i < 8; ++i) {
                    acc2[i][0] = fmaf(av[i], w4.x, acc2[i][0]);
                    acc2[i][1] = fmaf(av[i], w4.y, acc2[i][1]);
                    acc2[i][2] = fmaf(av[i], w4.z, acc2[i][2]);
                    acc2[i][3] = fmaf(av[i], w4.w, acc2[i][3]);
                }
            }
        }
    }
    if (act) {
        float4 b4 = *(const float4*)(bias + mhc * 4);
        #pragma unroll
        for (int i = 0; i < 8; ++i) {
            float4 o;
            o.x = acc2[i][0] + b4.x;
            o.y = acc2[i][1] + b4.y;
            o.z = acc2[i][2] + b4.z;
            o.w = acc2[i][3] + b4.w;
            *(float4*)(hb + (ml0 + i) * H + mhc * 4) = o;
        }
    }
}

// ---------------- fc1: partial[ks][b][p] = sum_{k in split} hd[b,k] * W[k,p] ----------------
__launch_bounds__(256, 3)
__global__ void fc1_kernel(const float* __restrict__ hd, const float* __restrict__ W,
                           float* __restrict__ partial)
{
    __shared__ float As[32 * 100];
    __shared__ float Bs[96 * 104];
    const int tid    = threadIdx.x;
    const int b0     = blockIdx.x * 32;
    const int ks     = blockIdx.y;
    const int kbase0 = ks * 2016;
    const bool act   = tid < 192;
    const int  bt    = tid / 24, pc = tid % 24;
    float acc[4][4];
    #pragma unroll
    for (int i = 0; i < 4; ++i) { acc[i][0] = acc[i][1] = acc[i][2] = acc[i][3] = 0.f; }

    for (int c = 0; c < 21; ++c) {
        int kb = kbase0 + c * 96;
        __syncthreads();
        for (int e = tid; e < 32 * 96; e += 256) {
            int r = e / 96, kk = e - r * 96;
            As[r * 100 + kk] = hd[(size_t)(b0 + r) * (L * H) + kb + kk];
        }
        for (int e = tid; e < 96 * 96; e += 256) {
            int kk = e / 96, p = e - kk * 96;
            Bs[kk * 104 + p] = W[(size_t)(kb + kk) * 96 + p];
        }
        __syncthreads();
        if (act) {
            #pragma unroll 4
            for (int kk = 0; kk < 96; ++kk) {
                float4 w4 = *(const float4*)(Bs + kk * 104 + pc * 4);
                #pragma unroll
                for (int i = 0; i < 4; ++i) {
                    float a = As[(bt * 4 + i) * 100 + kk];
                    acc[i][0] = fmaf(a, w4.x, acc[i][0]);
                    acc[i][1] = fmaf(a, w4.y, acc[i][1]);
                    acc[i][2] = fmaf(a, w4.z, acc[i][2]);
                    acc[i][3] = fmaf(a, w4.w, acc[i][3]);
                }
            }
        }
    }
    if (act) {
        #pragma unroll
        for (int i = 0; i < 4; ++i) {
            float* po = partial + (size_t)ks * (B * 96) + (size_t)(b0 + bt * 4 + i) * 96 + pc * 4;
            *(float4*)po = make_float4(acc[i][0], acc[i][1], acc[i][2], acc[i][3]);
        }
    }
}

__global__ void fc1red_kernel(const float* __restrict__ partial, const float* __restrict__ fb,
                              float* __restrict__ t1)
{
    int o = blockIdx.x * 256 + threadIdx.x;   // < 196608
    int p = o % 96;
    float s = fb[p];
    #pragma unroll
    for (int k = 0; k < 8; ++k) s += partial[(size_t)k * (B * 96) + o];
    t1[o] = s;
}

__launch_bounds__(256)
__global__ void fc2_kernel(const float* __restrict__ t1, const float* __restrict__ W,
                           const float* __restrict__ fb, float* __restrict__ out)
{
    __shared__ float Ws[96 * 100];
    const int tid = threadIdx.x;
    for (int e = tid; e < 96 * 96; e += 256) Ws[(e / 96) * 100 + (e % 96)] = W[e];
    __syncthreads();
    int o = blockIdx.x * 256 + tid;
    int b = o / 96, p = o - b * 96;
    const float* tr = t1 + b * 96;
    float acc = fb[p];
    #pragma unroll 4
    for (int h = 0; h < 96; ++h) acc = fmaf(tr[h], Ws[h * 100 + p], acc);
    out[o] = acc;
}

extern "C" void kernel_launch(void* const* d_in, const int* in_sizes, int n_in,
                              void* d_out, int out_size, void* d_ws, size_t ws_size,
                              hipStream_t stream)
{
    const float* x      = (const float*)d_in[0];
    const float* encW   = (const float*)d_in[1];
    const float* encb   = (const float*)d_in[2];
    const float* log_dt = (const float*)d_in[3];
    const float* lar    = (const float*)d_in[4];
    const float* aim    = (const float*)d_in[5];
    const float* cre    = (const float*)d_in[6];
    const float* cim    = (const float*)d_in[7];
    const float* dsk    = (const float*)d_in[8];
    const float* wout   = (const float*)d_in[9];
    const float* boutp  = (const float*)d_in[10];
    const float* lnw    = (const float*)d_in[11];
    const float* lnb    = (const float*)d_in[12];
    const float* decW   = (const float*)d_in[13];
    const float* decb   = (const float*)d_in[14];
    const float* fc1W   = (const float*)d_in[15];
    const float* fc1b   = (const float*)d_in[16];
    const float* fc2W   = (const float*)d_in[17];
    const float* fc2b   = (const float*)d_in[18];

    char*  ws      = (char*)d_ws;
    float* K       = (float*)(ws);                      // 258 KB
    float* partial = (float*)(ws + (size_t)(1 << 19));  // 6.3 MB
    float* t1      = (float*)(ws + (size_t)(7 << 20));  // 786 KB
    float* hbuf    = (float*)(ws + (size_t)(16 << 20)); // 132 MB

    kgen_kernel<<<NB * H, 64, 0, stream>>>(log_dt, lar, aim, cre, cim, K);
    enc_kernel<<<2048, 256, 0, stream>>>(x, encW, encb, hbuf);
    for (int i = 0; i < NB; ++i) {
        s4_block<<<B, 512, 0, stream>>>(hbuf, K + i * H * L, wout + i * H * H,
                                        boutp + i * H, dsk + i * H, lnw + i * H, lnb + i * H);
    }
    dec_kernel<<<B, 512, 0, stream>>>(hbuf, decW, decb);
    fc1_kernel<<<dim3(64, 8), 256, 0, stream>>>(hbuf, fc1W, partial);
    fc1red_kernel<<<768, 256, 0, stream>>>(partial, fc1b, t1);
    fc2_kernel<<<768, 256, 0, stream>>>(t1, fc2W, fc2b, (float*)d_out);
}